// Round 4
// baseline (75220.740 us; speedup 1.0000x reference)
//
#include <hip/hip_runtime.h>
#include <stdint.h>

#define BB 64
#define TT 64
#define OBSD 128
#define DD 512
#define NS 3
#define ACT 16
#define DONE 5
#define LN_EPS 1e-3f
#define NBLK 256

typedef unsigned short u16;
typedef __attribute__((ext_vector_type(8))) short short8;
typedef __attribute__((ext_vector_type(4))) float f32x4;

__device__ __forceinline__ float b2f(u16 u) {
    return __uint_as_float(((unsigned int)u) << 16);
}
__device__ __forceinline__ u16 f2b(float f) {
    unsigned int x = __float_as_uint(f);
    unsigned int r = x + 0x7fffu + ((x >> 16) & 1u);
    return (u16)(r >> 16);
}
__device__ __forceinline__ float sigm(float x) { return 1.f / (1.f + expf(-x)); }
__device__ __forceinline__ float ldin(const void* p, long i, int isf) {
    return isf ? ((const float*)p)[i] : b2f(((const u16*)p)[i]);
}
__device__ __forceinline__ void stout(void* p, long i, float v, int isf) {
    if (isf) ((float*)p)[i] = v; else ((u16*)p)[i] = f2b(v);
}

// ---------------- dtype detector + barrier init ----------------
__global__ void detect_k(const void* probe, int* flag, int* bar) {
    if (threadIdx.x == 0 && blockIdx.x == 0) {
        const u16* u = (const u16*)probe;
        int nz = 0, npl = 0;
        for (int j = 0; j < 128; ++j) {
            u16 v = u[2 * j];
            if (v == 0) { nz++; continue; }
            int e = (v >> 7) & 0xff;
            if (e >= 0x70 && e <= 0x88) npl++;
        }
        int nonzero = 128 - nz;
        *flag = (npl * 2 > nonzero) ? 0 : 1;  // 0 = bf16, 1 = f32
        bar[0] = 0;   // count
        bar[64] = 0;  // generation
    }
}

// ---------------- stage small params -> f32 ws ----------------
struct StageArgs { const void* src[16]; float* dst[16]; int n[16]; const int* flag; };
__global__ __launch_bounds__(256) void stage_k(StageArgs s) {
    int isf = *s.flag;
    int z = blockIdx.y;
    int i = blockIdx.x * 256 + threadIdx.x;
    if (s.src[z] && i < s.n[z]) s.dst[z][i] = ldin(s.src[z], i, isf);
}

// ---------------- elementwise convert -> bf16 ----------------
__global__ __launch_bounds__(256) void convb_k(const void* src, u16* dst, int n, const int* flag) {
    int isf = *flag;
    int i = blockIdx.x * 256 + threadIdx.x;
    if (i < n) dst[i] = isf ? f2b(((const float*)src)[i]) : ((const u16*)src)[i];
}

// ---------------- transpose [K,N] -> bf16 [N,K] ----------------
__global__ __launch_bounds__(256) void transpose_k(const void* in, u16* out, int K, int N,
                                                   const int* flag) {
    __shared__ u16 tile[32][33];
    int isf = *flag;
    long zoff = (long)blockIdx.z * K * N;
    int kb = blockIdx.y * 32, nb = blockIdx.x * 32;
    int tx = threadIdx.x & 31, ty = threadIdx.x >> 5;
    for (int r = ty; r < 32; r += 8) {
        long idx = zoff + (long)(kb + r) * N + nb + tx;
        tile[r][tx] = isf ? f2b(((const float*)in)[idx]) : ((const u16*)in)[idx];
    }
    __syncthreads();
    for (int r = ty; r < 32; r += 8)
        out[zoff + (long)(nb + r) * K + kb + tx] = tile[tx][r];
}

// ---------------- init: task_emb gather + m state ----------------
__global__ __launch_bounds__(256) void init_k(const void* emb, const int* env, const void* prevm,
                                              float* task_f, u16* task_b, u16* m_b, float* m_f,
                                              const int* flag) {
    int isf = *flag;
    int b = blockIdx.x, tid = threadIdx.x;
    int e = env[b];
    for (int j = tid; j < DD; j += 256) {
        float v = ldin(emb, (long)e * DD + j, isf);
        task_f[b * DD + j] = v;
        task_b[b * DD + j] = f2b(v);
    }
    for (int j = tid; j < NS * DD; j += 256) {
        float v = ldin(prevm, (long)b * NS * DD + j, isf);
        m_b[b * NS * DD + j] = f2b(v);
        m_f[b * NS * DD + j] = v;
    }
}

// ---------------- obs GEMM (standalone, big grid) ----------------
__global__ __launch_bounds__(256) void obsgemm_k(const u16* __restrict__ X, const u16* __restrict__ Wt,
                                                 const float* __restrict__ bias,
                                                 float* __restrict__ yf, u16* __restrict__ yb) {
    const int lane = threadIdx.x & 63;
    const int wave = threadIdx.x >> 6;
    const int l16 = lane & 15;
    const int quad = lane >> 4;
    const int n = blockIdx.x * 64 + wave * 16 + l16;
    const int m_base = blockIdx.y * 64;

    f32x4 acc0 = {0.f, 0.f, 0.f, 0.f};
    f32x4 acc1 = acc0, acc2 = acc0, acc3 = acc0;
    const u16* a0 = X + (long)(m_base + l16) * OBSD + quad * 8;
    const u16* a1 = a0 + (long)16 * OBSD;
    const u16* a2 = a0 + (long)32 * OBSD;
    const u16* a3 = a0 + (long)48 * OBSD;
    const u16* wp = Wt + (long)n * OBSD + quad * 8;
    for (int k = 0; k < OBSD; k += 32) {
        short8 av0 = *(const short8*)(a0 + k);
        short8 av1 = *(const short8*)(a1 + k);
        short8 av2 = *(const short8*)(a2 + k);
        short8 av3 = *(const short8*)(a3 + k);
        short8 bv = *(const short8*)(wp + k);
        acc0 = __builtin_amdgcn_mfma_f32_16x16x32_bf16(av0, bv, acc0, 0, 0, 0);
        acc1 = __builtin_amdgcn_mfma_f32_16x16x32_bf16(av1, bv, acc1, 0, 0, 0);
        acc2 = __builtin_amdgcn_mfma_f32_16x16x32_bf16(av2, bv, acc2, 0, 0, 0);
        acc3 = __builtin_amdgcn_mfma_f32_16x16x32_bf16(av3, bv, acc3, 0, 0, 0);
    }
    float bb = bias[n];
    f32x4 accs[4] = {acc0, acc1, acc2, acc3};
#pragma unroll
    for (int mt = 0; mt < 4; ++mt)
#pragma unroll
        for (int r = 0; r < 4; ++r) {
            int m = m_base + mt * 16 + quad * 4 + r;
            float v = accs[mt][r] + bb;
            yf[(long)m * DD + n] = v;
            yb[(long)m * DD + n] = f2b(v);
        }
}

// ================= persistent kernel (plain launch, 1 block/CU) =================
struct GSeg { const u16* p; int rs; int zs; };
struct SH { float arow[2048]; float red[256]; float u[512]; float sl[16]; };

__device__ __forceinline__ void gbar(int* cnt, int* gen) {
    __syncthreads();
    __threadfence();
    if (threadIdx.x == 0) {
        int g0 = __hip_atomic_load(gen, __ATOMIC_RELAXED, __HIP_MEMORY_SCOPE_AGENT);
        if (__hip_atomic_fetch_add(cnt, 1, __ATOMIC_ACQ_REL, __HIP_MEMORY_SCOPE_AGENT) == NBLK - 1) {
            __hip_atomic_store(cnt, 0, __ATOMIC_RELAXED, __HIP_MEMORY_SCOPE_AGENT);
            __hip_atomic_store(gen, g0 + 1, __ATOMIC_RELEASE, __HIP_MEMORY_SCOPE_AGENT);
        }
        while (__hip_atomic_load(gen, __ATOMIC_ACQUIRE, __HIP_MEMORY_SCOPE_AGENT) == g0)
            __builtin_amdgcn_s_sleep(2);
    }
    __syncthreads();
}

__device__ __forceinline__ float block_sum(float v, float* red) {
    red[threadIdx.x] = v;
    __syncthreads();
    for (int s = 128; s > 0; s >>= 1) {
        if (threadIdx.x < s) red[threadIdx.x] += red[threadIdx.x + s];
        __syncthreads();
    }
    float r = red[0];
    __syncthreads();
    return r;
}

// split-K GEMM: kchunk = 256, ksplit = K/256; partials f32 [ksplit][nz*64][N]
// grid-stride over tile ids so correctness never depends on NBLK >= tiles.
__device__ void gemm_phase(int bid, const GSeg* segs, const u16* Wt,
                           int K, int N, int nz, float* part) {
    const int ksplit = K >> 8;
    const int ntiles = N >> 6;
    const int total = ntiles * nz * ksplit;
    const int lane = threadIdx.x & 63;
    const int wave = threadIdx.x >> 6;
    const int l16 = lane & 15, quad = lane >> 4;
    for (int id = bid; id < total; id += NBLK) {
        const int kc = id % ksplit;
        const int tz = id / ksplit;
        const int ntile = tz % ntiles;
        const int z = tz / ntiles;
        const int n = ntile * 64 + wave * 16 + l16;
        const int k0 = kc << 8;
        const GSeg sg = segs[k0 >> 9];
        const int koff = k0 & 511;
        const u16* ab = sg.p + (long)z * sg.zs + koff + quad * 8;
        const u16* a0 = ab + (long)l16 * sg.rs;
        const u16* a1 = a0 + (long)16 * sg.rs;
        const u16* a2 = a0 + (long)32 * sg.rs;
        const u16* a3 = a0 + (long)48 * sg.rs;
        const u16* wp = Wt + (long)n * K + k0 + quad * 8;
        f32x4 acc0 = {0.f, 0.f, 0.f, 0.f};
        f32x4 acc1 = acc0, acc2 = acc0, acc3 = acc0;
        for (int k = 0; k < 256; k += 32) {
            short8 av0 = *(const short8*)(a0 + k);
            short8 av1 = *(const short8*)(a1 + k);
            short8 av2 = *(const short8*)(a2 + k);
            short8 av3 = *(const short8*)(a3 + k);
            short8 bv = *(const short8*)(wp + k);
            acc0 = __builtin_amdgcn_mfma_f32_16x16x32_bf16(av0, bv, acc0, 0, 0, 0);
            acc1 = __builtin_amdgcn_mfma_f32_16x16x32_bf16(av1, bv, acc1, 0, 0, 0);
            acc2 = __builtin_amdgcn_mfma_f32_16x16x32_bf16(av2, bv, acc2, 0, 0, 0);
            acc3 = __builtin_amdgcn_mfma_f32_16x16x32_bf16(av3, bv, acc3, 0, 0, 0);
        }
        float* pr = part + (long)kc * (nz * 64 * N) + (long)(z * 64) * N + n;
        f32x4 accs[4] = {acc0, acc1, acc2, acc3};
#pragma unroll
        for (int mt = 0; mt < 4; ++mt)
#pragma unroll
            for (int r = 0; r < 4; ++r)
                pr[(long)(mt * 16 + quad * 4 + r) * N] = accs[mt][r];
    }
}

// reduce ksplit partials + bias + relu -> bf16 (N fixed 2048, M=64)
__device__ void reduce_phase(int bid, const float* part, int ksplit,
                             const float* bias, u16* outb) {
    const int MN = 64 * 2048;
    for (int i = bid * 256 + threadIdx.x; i < MN; i += NBLK * 256) {
        float s = bias[i & 2047];
        for (int kc = 0; kc < ksplit; ++kc) s += part[(long)kc * MN + i];
        outb[i] = f2b(s > 0.f ? s : 0.f);
    }
}

// gate with folded partial-reduce; out rows stride NS*DD
__device__ void gate_phase(int bid, SH& sh, const float* part, int ksplit, int N, int W1,
                           const float* bias, const float* gw, const float* gb,
                           const float* s0, int s0_rs, const float* s1, int s1_rs,
                           float* out_f, u16* out_b) {
    if (bid >= BB) return;
    const int b = bid, tid = threadIdx.x;
    const int MN = 64 * N;
    float s = 0.f, ss = 0.f;
    for (int j = tid; j < N; j += 256) {
        float v = bias[j];
        for (int kc = 0; kc < ksplit; ++kc) v += part[(long)kc * MN + (long)b * N + j];
        sh.arow[j] = v;
        if (j < W1) { s += v; ss += v * v; }
    }
    float tot = block_sum(s, sh.red);
    float tot2 = block_sum(ss, sh.red);
    float mu = tot / (float)W1;
    float var = tot2 / (float)W1 - mu * mu;
    float inv = rsqrtf(var + LN_EPS);

    float s2 = 0.f, ss2 = 0.f;
    for (int d = tid; d < DD; d += 256) {
        float g0 = sigm((sh.arow[d] - mu) * inv * gw[d] + gb[d]);
        float val = g0 * s0[(long)b * s0_rs + d];
        if (s1) {
            float g1 = sigm((sh.arow[DD + d] - mu) * inv * gw[DD + d] + gb[DD + d]);
            val += g1 * s1[(long)b * s1_rs + d];
        }
        float gc = sigm((sh.arow[W1 - DD + d] - mu) * inv * gw[W1 - DD + d] + gb[W1 - DD + d]);
        val += gc * sh.arow[W1 + d];
        sh.u[d] = val;
        s2 += val; ss2 += val * val;
    }
    float t2 = block_sum(s2, sh.red);
    float t22 = block_sum(ss2, sh.red);
    float mu2 = t2 / (float)DD;
    float var2 = t22 / (float)DD - mu2 * mu2;
    float inv2 = rsqrtf(var2 + LN_EPS);
    for (int d = tid; d < DD; d += 256) {
        float v = (sh.u[d] - mu2) * inv2;
        long o = (long)b * (NS * DD) + d;
        out_f[o] = v;
        out_b[o] = f2b(v);
    }
}

// pbm with folded gd-partial reduce + leaky
__device__ void pbm_phase(int bid, SH& sh, const float* part,
                          const float* bd1, const float* Wd2, const float* bd2,
                          const float* cand_f, float* m_f, u16* m_b, float* chl_f,
                          float* pp, void* out, long ph_base, int isf) {
    if (bid >= BB) return;
    const int b = bid, tid = threadIdx.x;
    const int MN = 192 * 512;
    float dot[3];
    for (int n = 0; n < 3; ++n) {
        float sacc = 0.f;
        for (int k = tid; k < 512; k += 256) {
            float h = bd1[k];
            for (int kc = 0; kc < 8; ++kc) h += part[(long)kc * MN + (long)(n * 64 + b) * 512 + k];
            h = h > 0.f ? h : 0.3f * h;
            sacc += h * Wd2[k];
        }
        dot[n] = block_sum(sacc, sh.red);
    }
    if (tid == 0) {
        float bd = bd2[0];
        float b0 = sigm(dot[0] + bd), b1 = sigm(dot[1] + bd), b2 = sigm(dot[2] + bd);
        float ph0 = (1.f - b2) * (1.f - b1) * (1.f - b0);
        float ph1 = b0 * (1.f - b2) * (1.f - b1);
        float ph2 = b1 * (1.f - b2);
        float ph3 = b2;
        float sum = fmaxf(ph1 + ph2 + ph3, 1e-30f);
        float p0 = ph1 / sum, p1 = ph2 / sum, p2 = ph3 / sum;
        sh.sl[0] = p0 + p1 + p2; sh.sl[1] = p1 + p2; sh.sl[2] = p2;
        pp[b * 4 + 0] = p0; pp[b * 4 + 1] = p1;
        pp[b * 4 + 2] = p2; pp[b * 4 + 3] = ph0;
        long ob = ph_base + (long)b * (TT * (NS + 1));
        stout(out, ob + 0, ph0, isf);
        stout(out, ob + 1, ph1, isf);
        stout(out, ob + 2, ph2, isf);
        stout(out, ob + 3, ph3, isf);
    }
    __syncthreads();
    for (int idx = tid; idx < NS * DD; idx += 256) {
        int n = idx >> 9, d = idx & (DD - 1);
        float r = sh.sl[n];
        long o = (long)b * NS * DD + idx;
        float v = m_f[o] * (1.f - r) + cand_f[o] * r;
        m_f[o] = v;
        m_b[o] = f2b(v);
        if (n == 0) chl_f[(long)b * NS * DD + d] = v;
    }
}

__device__ void final_phase(int bid, SH& sh, const float* chl, const float* pp,
                            const float* task, const float* inp,
                            const float* Wa, const float* ba,
                            void* out, long o_base, int isf) {
    if (bid >= BB) return;
    const int b = bid, tid = threadIdx.x;
    const float* pb = pp + b * 4;
    const float* c = chl + (long)b * NS * DD;
    for (int d = tid; d < DD; d += 256) {
        sh.arow[d] = pb[0] * c[d] + pb[1] * c[DD + d] + pb[2] * c[2 * DD + d];
        sh.arow[DD + d] = task[b * DD + d];
        sh.arow[2 * DD + d] = inp[(long)b * (TT * DD) + d];
    }
    __syncthreads();
    if (tid < 240) {
        int a = tid >> 4, kk = tid & 15;
        float sacc = 0.f;
        for (int k = kk; k < 3 * DD; k += 16) sacc += sh.arow[k] * Wa[k * (ACT - 1) + a];
        sacc += __shfl_down(sacc, 8);
        sacc += __shfl_down(sacc, 4);
        sacc += __shfl_down(sacc, 2);
        sacc += __shfl_down(sacc, 1);
        if (kk == 0) sh.sl[a] = sacc + ba[a];
    }
    __syncthreads();
    if (tid == 0) {
        float mx = -1e30f;
        for (int a = 0; a < ACT - 1; ++a) mx = fmaxf(mx, sh.sl[a]);
        float se = 0.f;
        for (int a = 0; a < ACT - 1; ++a) se += expf(sh.sl[a] - mx);
        float lse = logf(se);
        float pe = pb[3];
        pe = fminf(fmaxf(pe, 1e-6f), 1.f - 1e-6f);
        float l1me = logf(1.f - pe);
        long ob = o_base + (long)b * (TT * ACT);
        for (int a = 0; a < ACT - 1; ++a) {
            float lg = sh.sl[a] - mx - lse + l1me;
            int pos = (a < DONE) ? a : a + 1;
            stout(out, ob + pos, lg, isf);
        }
        stout(out, ob + DONE, logf(pe), isf);
    }
}

struct PArgs {
    const u16 *comW1t, *comW2t, *decW1t, *decW2t, *Wd1t;
    const float *b_comb1, *b_comb2, *g_com, *beta_com;
    const float *b_decb1, *b_decb2, *g_dec, *beta_dec;
    const float *b_bd1, *w_Wd2, *b_bd2, *w_Wa, *b_ba;
    const u16 *obs_b_inp; const float *obs_f_inp;
    const u16 *task_b; const float *task_f;
    u16 *m_b; float *m_f; u16 *cand_b; float *cand_f;
    u16 *chl_b; float *chl_f; u16 *a1_b;
    float *part; float *pp;
    void *out; const int *flag;
    int *bar;
};

__global__ __launch_bounds__(256, 1) void persist_k(PArgs A) {
    __shared__ SH sh;
    const int bid = blockIdx.x;
    int* cnt = A.bar;
    int* gen = A.bar + 64;
    const int isf = *A.flag;

    for (int t = 0; t < TT; ++t) {
        const u16* inpb = A.obs_b_inp + t * DD;
        const float* inpf = A.obs_f_inp + t * DD;

        for (int ii = NS - 1; ii >= 0; --ii) {
            {
                GSeg segs[4] = {
                    { ii == NS - 1 ? inpb : A.cand_b + (ii + 1) * DD,
                      ii == NS - 1 ? TT * DD : NS * DD, 0 },
                    { A.m_b + ii * DD, NS * DD, 0 },
                    { inpb, TT * DD, 0 },
                    { A.task_b, DD, 0 } };
                gemm_phase(bid, segs, A.comW1t + (long)ii * 2048 * 2048, 2048, 2048, 1, A.part);
            }
            gbar(cnt, gen);
            reduce_phase(bid, A.part, 8, A.b_comb1 + ii * 2048, A.a1_b);
            gbar(cnt, gen);
            {
                GSeg segs[4] = { {A.a1_b, 2048, 0}, {A.a1_b + 512, 2048, 0},
                                 {A.a1_b + 1024, 2048, 0}, {A.a1_b + 1536, 2048, 0} };
                gemm_phase(bid, segs, A.comW2t + (long)ii * 2048 * 2048, 2048, 2048, 1, A.part);
            }
            gbar(cnt, gen);
            gate_phase(bid, sh, A.part, 8, 2048, 1536,
                       A.b_comb2 + ii * 2048, A.g_com + ii * 1536, A.beta_com + ii * 1536,
                       ii == NS - 1 ? inpf : A.cand_f + (ii + 1) * DD,
                       ii == NS - 1 ? TT * DD : NS * DD,
                       A.m_f + ii * DD, NS * DD,
                       A.cand_f + ii * DD, A.cand_b + ii * DD);
            gbar(cnt, gen);
        }

        {
            GSeg segs[4] = { {inpb, TT * DD, 0}, {A.task_b, DD, 0},
                             {A.m_b, NS * DD, DD}, {A.cand_b, NS * DD, DD} };
            gemm_phase(bid, segs, A.Wd1t, 2048, 512, 3, A.part);
        }
        gbar(cnt, gen);
        pbm_phase(bid, sh, A.part, A.b_bd1, A.w_Wd2, A.b_bd2, A.cand_f,
                  A.m_f, A.m_b, A.chl_f, A.pp, A.out,
                  (long)BB * TT * ACT + (long)t * (NS + 1), isf);
        gbar(cnt, gen);

        for (int j = 0; j < 2; ++j) {
            {
                GSeg segs[3] = { { j == 0 ? A.m_b : A.chl_b + DD, NS * DD, 0 },
                                 { inpb, TT * DD, 0 },
                                 { A.task_b, DD, 0 } };
                gemm_phase(bid, segs, A.decW1t + (long)j * 2048 * 1536, 1536, 2048, 1, A.part);
            }
            gbar(cnt, gen);
            reduce_phase(bid, A.part, 6, A.b_decb1 + j * 2048, A.a1_b);
            gbar(cnt, gen);
            {
                GSeg segs[4] = { {A.a1_b, 2048, 0}, {A.a1_b + 512, 2048, 0},
                                 {A.a1_b + 1024, 2048, 0}, {A.a1_b + 1536, 2048, 0} };
                gemm_phase(bid, segs, A.decW2t + (long)j * 1536 * 2048, 2048, 1536, 1, A.part);
            }
            gbar(cnt, gen);
            gate_phase(bid, sh, A.part, 8, 1536, 1024,
                       A.b_decb2 + j * 1536, A.g_dec + j * 1024, A.beta_dec + j * 1024,
                       j == 0 ? A.m_f : A.chl_f + DD, NS * DD,
                       nullptr, 0,
                       A.chl_f + (j + 1) * DD, A.chl_b + (j + 1) * DD);
            gbar(cnt, gen);
        }

        final_phase(bid, sh, A.chl_f, A.pp, A.task_f, inpf, A.w_Wa, A.b_ba,
                    A.out, (long)t * ACT, isf);
        gbar(cnt, gen);
    }
}

// ---------------- host ----------------
extern "C" void kernel_launch(void* const* d_in, const int* in_sizes, int n_in,
                              void* d_out, int out_size, void* d_ws, size_t ws_size,
                              hipStream_t stream) {
    const void* obs = d_in[0];
    const int* env = (const int*)d_in[1];
    const void* prevm = d_in[2];
    const void* emb = d_in[4];
    const void* Wobs = d_in[5];
    const void* bobs = d_in[6];
    const void* comW1 = d_in[7];
    const void* comb1 = d_in[8];
    const void* comW2 = d_in[9];
    const void* comb2 = d_in[10];
    const void* comg = d_in[11];
    const void* combeta = d_in[12];
    const void* decW1 = d_in[13];
    const void* decb1 = d_in[14];
    const void* decW2 = d_in[15];
    const void* decb2 = d_in[16];
    const void* decg = d_in[17];
    const void* decbeta = d_in[18];
    const void* Wd1 = d_in[19];
    const void* bd1 = d_in[20];
    const void* Wd2 = d_in[21];
    const void* bd2 = d_in[22];
    const void* Wa = d_in[23];
    const void* ba = d_in[24];

    char* p = (char*)d_ws;
    auto carve = [&](size_t bytes) -> char* {
        char* r = p;
        p += (bytes + 255) & ~(size_t)255;
        return r;
    };
    int* flag = (int*)carve(256);
    int* bar = (int*)carve(512);
    u16* comW1t = (u16*)carve(3ull * 2048 * 2048 * 2);
    u16* comW2t = (u16*)carve(3ull * 2048 * 2048 * 2);
    u16* decW1t = (u16*)carve(2ull * 2048 * 1536 * 2);
    u16* decW2t = (u16*)carve(2ull * 1536 * 2048 * 2);
    u16* Wd1t = (u16*)carve(512ull * 2048 * 2);
    u16* Wobst = (u16*)carve(512ull * 128 * 2);
    u16* obs_b = (u16*)carve((size_t)BB * TT * OBSD * 2);
    float* obs_inp_f = (float*)carve((size_t)BB * TT * DD * 4);
    u16* obs_inp_b = (u16*)carve((size_t)BB * TT * DD * 2);
    float* task_f = (float*)carve((size_t)BB * DD * 4);
    u16* task_b = (u16*)carve((size_t)BB * DD * 2);
    float* m_f = (float*)carve((size_t)BB * NS * DD * 4);
    u16* m_b = (u16*)carve((size_t)BB * NS * DD * 2);
    float* cand_f = (float*)carve((size_t)BB * NS * DD * 4);
    u16* cand_b = (u16*)carve((size_t)BB * NS * DD * 2);
    float* chl_f = (float*)carve((size_t)BB * NS * DD * 4);
    u16* chl_b = (u16*)carve((size_t)BB * NS * DD * 2);
    u16* a1_b = (u16*)carve((size_t)BB * 2048 * 2);
    float* part = (float*)carve(8ull * 64 * 2048 * 4);
    float* pp = (float*)carve((size_t)BB * 4 * 4);
    float* st_bobs = (float*)carve(512 * 4);
    float* st_comb1 = (float*)carve(3 * 2048 * 4);
    float* st_comb2 = (float*)carve(3 * 2048 * 4);
    float* st_comg = (float*)carve(3 * 1536 * 4);
    float* st_combeta = (float*)carve(3 * 1536 * 4);
    float* st_decb1 = (float*)carve(2 * 2048 * 4);
    float* st_decb2 = (float*)carve(2 * 1536 * 4);
    float* st_decg = (float*)carve(2 * 1024 * 4);
    float* st_decbeta = (float*)carve(2 * 1024 * 4);
    float* st_bd1 = (float*)carve(512 * 4);
    float* st_Wd2 = (float*)carve(512 * 4);
    float* st_bd2 = (float*)carve(256);
    float* st_Wa = (float*)carve(1536 * 15 * 4);
    float* st_ba = (float*)carve(15 * 4);

    dim3 blk(256);

    detect_k<<<dim3(1), dim3(64), 0, stream>>>(Wobs, flag, bar);

    {
        StageArgs sa{};
        const void* srcs[14] = {bobs, comb1, comb2, comg, combeta, decb1, decb2,
                                decg, decbeta, bd1, Wd2, bd2, Wa, ba};
        float* dsts[14] = {st_bobs, st_comb1, st_comb2, st_comg, st_combeta, st_decb1,
                           st_decb2, st_decg, st_decbeta, st_bd1, st_Wd2, st_bd2, st_Wa, st_ba};
        int ns[14] = {512, 6144, 6144, 4608, 4608, 4096, 3072, 2048, 2048, 512, 512, 1, 23040, 15};
        for (int i = 0; i < 14; ++i) { sa.src[i] = srcs[i]; sa.dst[i] = dsts[i]; sa.n[i] = ns[i]; }
        sa.flag = flag;
        stage_k<<<dim3(90, 14, 1), blk, 0, stream>>>(sa);
    }

    transpose_k<<<dim3(16, 4, 1), blk, 0, stream>>>(Wobs, Wobst, 128, 512, flag);
    transpose_k<<<dim3(64, 64, 3), blk, 0, stream>>>(comW1, comW1t, 2048, 2048, flag);
    transpose_k<<<dim3(64, 64, 3), blk, 0, stream>>>(comW2, comW2t, 2048, 2048, flag);
    transpose_k<<<dim3(64, 48, 2), blk, 0, stream>>>(decW1, decW1t, 1536, 2048, flag);
    transpose_k<<<dim3(48, 64, 2), blk, 0, stream>>>(decW2, decW2t, 2048, 1536, flag);
    transpose_k<<<dim3(16, 64, 1), blk, 0, stream>>>(Wd1, Wd1t, 2048, 512, flag);
    convb_k<<<dim3((BB * TT * OBSD + 255) / 256), blk, 0, stream>>>(obs, obs_b, BB * TT * OBSD, flag);
    init_k<<<dim3(BB), blk, 0, stream>>>(emb, env, prevm, task_f, task_b, m_b, m_f, flag);
    obsgemm_k<<<dim3(DD / 64, (BB * TT) / 64, 1), blk, 0, stream>>>(obs_b, Wobst, st_bobs,
                                                                    obs_inp_f, obs_inp_b);

    PArgs pa{};
    pa.comW1t = comW1t; pa.comW2t = comW2t; pa.decW1t = decW1t; pa.decW2t = decW2t; pa.Wd1t = Wd1t;
    pa.b_comb1 = st_comb1; pa.b_comb2 = st_comb2; pa.g_com = st_comg; pa.beta_com = st_combeta;
    pa.b_decb1 = st_decb1; pa.b_decb2 = st_decb2; pa.g_dec = st_decg; pa.beta_dec = st_decbeta;
    pa.b_bd1 = st_bd1; pa.w_Wd2 = st_Wd2; pa.b_bd2 = st_bd2; pa.w_Wa = st_Wa; pa.b_ba = st_ba;
    pa.obs_b_inp = obs_inp_b; pa.obs_f_inp = obs_inp_f;
    pa.task_b = task_b; pa.task_f = task_f;
    pa.m_b = m_b; pa.m_f = m_f; pa.cand_b = cand_b; pa.cand_f = cand_f;
    pa.chl_b = chl_b; pa.chl_f = chl_f; pa.a1_b = a1_b;
    pa.part = part; pa.pp = pp;
    pa.out = d_out; pa.flag = flag;
    pa.bar = bar;

    persist_k<<<dim3(NBLK), dim3(256), 0, stream>>>(pa);
}

// Round 5
// 24558.232 us; speedup vs baseline: 3.0630x; 3.0630x over previous
//
#include <hip/hip_runtime.h>
#include <stdint.h>

#define BB 64
#define TT 64
#define OBSD 128
#define DD 512
#define NS 3
#define ACT 16
#define DONE 5
#define LN_EPS 1e-3f
#define NBLK 256

typedef unsigned short u16;
typedef __attribute__((ext_vector_type(8))) short short8;
typedef __attribute__((ext_vector_type(4))) float f32x4;

__device__ __forceinline__ float b2f(u16 u) {
    return __uint_as_float(((unsigned int)u) << 16);
}
__device__ __forceinline__ u16 f2b(float f) {
    unsigned int x = __float_as_uint(f);
    unsigned int r = x + 0x7fffu + ((x >> 16) & 1u);
    return (u16)(r >> 16);
}
__device__ __forceinline__ float sigm(float x) { return 1.f / (1.f + expf(-x)); }
__device__ __forceinline__ float ldin(const void* p, long i, int isf) {
    return isf ? ((const float*)p)[i] : b2f(((const u16*)p)[i]);
}
__device__ __forceinline__ void stout(void* p, long i, float v, int isf) {
    if (isf) ((float*)p)[i] = v; else ((u16*)p)[i] = f2b(v);
}
// nontemporal helpers (perf hint only; correctness comes from barrier fences)
__device__ __forceinline__ short8 ntldv(const u16* p) {
    return __builtin_nontemporal_load((const short8*)p);
}
__device__ __forceinline__ float ntldf(const float* p) { return __builtin_nontemporal_load(p); }
__device__ __forceinline__ void ntstf(float* p, float v) { __builtin_nontemporal_store(v, p); }
__device__ __forceinline__ void ntstu(u16* p, u16 v) { __builtin_nontemporal_store(v, p); }

// ---------------- dtype detector + barrier init ----------------
__global__ void detect_k(const void* probe, int* flag, int* bar) {
    if (threadIdx.x == 0 && blockIdx.x == 0) {
        const u16* u = (const u16*)probe;
        int nz = 0, npl = 0;
        for (int j = 0; j < 128; ++j) {
            u16 v = u[2 * j];
            if (v == 0) { nz++; continue; }
            int e = (v >> 7) & 0xff;
            if (e >= 0x70 && e <= 0x88) npl++;
        }
        int nonzero = 128 - nz;
        *flag = (npl * 2 > nonzero) ? 0 : 1;  // 0 = bf16, 1 = f32
        bar[0] = 0;   // count
        bar[64] = 0;  // generation
    }
}

// ---------------- stage small params -> f32 ws ----------------
struct StageArgs { const void* src[16]; float* dst[16]; int n[16]; const int* flag; };
__global__ __launch_bounds__(256) void stage_k(StageArgs s) {
    int isf = *s.flag;
    int z = blockIdx.y;
    int i = blockIdx.x * 256 + threadIdx.x;
    if (s.src[z] && i < s.n[z]) s.dst[z][i] = ldin(s.src[z], i, isf);
}

// ---------------- elementwise convert -> bf16 ----------------
__global__ __launch_bounds__(256) void convb_k(const void* src, u16* dst, int n, const int* flag) {
    int isf = *flag;
    int i = blockIdx.x * 256 + threadIdx.x;
    if (i < n) dst[i] = isf ? f2b(((const float*)src)[i]) : ((const u16*)src)[i];
}

// ---------------- transpose [K,N] -> bf16 [N,K] ----------------
__global__ __launch_bounds__(256) void transpose_k(const void* in, u16* out, int K, int N,
                                                   const int* flag) {
    __shared__ u16 tile[32][33];
    int isf = *flag;
    long zoff = (long)blockIdx.z * K * N;
    int kb = blockIdx.y * 32, nb = blockIdx.x * 32;
    int tx = threadIdx.x & 31, ty = threadIdx.x >> 5;
    for (int r = ty; r < 32; r += 8) {
        long idx = zoff + (long)(kb + r) * N + nb + tx;
        tile[r][tx] = isf ? f2b(((const float*)in)[idx]) : ((const u16*)in)[idx];
    }
    __syncthreads();
    for (int r = ty; r < 32; r += 8)
        out[zoff + (long)(nb + r) * K + kb + tx] = tile[tx][r];
}

// ---------------- init: task_emb gather + m state ----------------
__global__ __launch_bounds__(256) void init_k(const void* emb, const int* env, const void* prevm,
                                              float* task_f, u16* task_b, u16* m_b, float* m_f,
                                              const int* flag) {
    int isf = *flag;
    int b = blockIdx.x, tid = threadIdx.x;
    int e = env[b];
    for (int j = tid; j < DD; j += 256) {
        float v = ldin(emb, (long)e * DD + j, isf);
        task_f[b * DD + j] = v;
        task_b[b * DD + j] = f2b(v);
    }
    for (int j = tid; j < NS * DD; j += 256) {
        float v = ldin(prevm, (long)b * NS * DD + j, isf);
        m_b[b * NS * DD + j] = f2b(v);
        m_f[b * NS * DD + j] = v;
    }
}

// ---------------- obs GEMM (standalone, big grid) ----------------
__global__ __launch_bounds__(256) void obsgemm_k(const u16* __restrict__ X, const u16* __restrict__ Wt,
                                                 const float* __restrict__ bias,
                                                 float* __restrict__ yf, u16* __restrict__ yb) {
    const int lane = threadIdx.x & 63;
    const int wave = threadIdx.x >> 6;
    const int l16 = lane & 15;
    const int quad = lane >> 4;
    const int n = blockIdx.x * 64 + wave * 16 + l16;
    const int m_base = blockIdx.y * 64;

    f32x4 acc0 = {0.f, 0.f, 0.f, 0.f};
    f32x4 acc1 = acc0, acc2 = acc0, acc3 = acc0;
    const u16* a0 = X + (long)(m_base + l16) * OBSD + quad * 8;
    const u16* a1 = a0 + (long)16 * OBSD;
    const u16* a2 = a0 + (long)32 * OBSD;
    const u16* a3 = a0 + (long)48 * OBSD;
    const u16* wp = Wt + (long)n * OBSD + quad * 8;
    for (int k = 0; k < OBSD; k += 32) {
        short8 av0 = *(const short8*)(a0 + k);
        short8 av1 = *(const short8*)(a1 + k);
        short8 av2 = *(const short8*)(a2 + k);
        short8 av3 = *(const short8*)(a3 + k);
        short8 bv = *(const short8*)(wp + k);
        acc0 = __builtin_amdgcn_mfma_f32_16x16x32_bf16(av0, bv, acc0, 0, 0, 0);
        acc1 = __builtin_amdgcn_mfma_f32_16x16x32_bf16(av1, bv, acc1, 0, 0, 0);
        acc2 = __builtin_amdgcn_mfma_f32_16x16x32_bf16(av2, bv, acc2, 0, 0, 0);
        acc3 = __builtin_amdgcn_mfma_f32_16x16x32_bf16(av3, bv, acc3, 0, 0, 0);
    }
    float bb = bias[n];
    f32x4 accs[4] = {acc0, acc1, acc2, acc3};
#pragma unroll
    for (int mt = 0; mt < 4; ++mt)
#pragma unroll
        for (int r = 0; r < 4; ++r) {
            int m = m_base + mt * 16 + quad * 4 + r;
            float v = accs[mt][r] + bb;
            yf[(long)m * DD + n] = v;
            yb[(long)m * DD + n] = f2b(v);
        }
}

// ================= persistent kernel (plain launch, 1 block/CU) =================
struct GSeg { const u16* p; int rs; int zs; };
struct SH { float arow[2048]; float red[256]; float u[512]; float sl[16]; };

// One release fence + one acquire fence per block per barrier. Spin uses
// RELAXED agent-scope loads (scope bits route to LLC — no per-poll L2
// invalidate); hedge: one ACQUIRE poll every 64 relaxed polls.
__device__ __forceinline__ void gbar(int* cnt, int* gen) {
    __syncthreads();
    if (threadIdx.x == 0) {
        __builtin_amdgcn_fence(__ATOMIC_RELEASE, "agent");
        int g0 = __hip_atomic_load(gen, __ATOMIC_RELAXED, __HIP_MEMORY_SCOPE_AGENT);
        if (__hip_atomic_fetch_add(cnt, 1, __ATOMIC_RELAXED, __HIP_MEMORY_SCOPE_AGENT) == NBLK - 1) {
            __hip_atomic_store(cnt, 0, __ATOMIC_RELAXED, __HIP_MEMORY_SCOPE_AGENT);
            __hip_atomic_store(gen, g0 + 1, __ATOMIC_RELEASE, __HIP_MEMORY_SCOPE_AGENT);
        } else {
            int it = 0;
            for (;;) {
                int g;
                if ((++it & 63) == 0)
                    g = __hip_atomic_load(gen, __ATOMIC_ACQUIRE, __HIP_MEMORY_SCOPE_AGENT);
                else
                    g = __hip_atomic_load(gen, __ATOMIC_RELAXED, __HIP_MEMORY_SCOPE_AGENT);
                if (g != g0) break;
                __builtin_amdgcn_s_sleep(8);
            }
        }
        __builtin_amdgcn_fence(__ATOMIC_ACQUIRE, "agent");
    }
    __syncthreads();
}

__device__ __forceinline__ float block_sum(float v, float* red) {
    red[threadIdx.x] = v;
    __syncthreads();
    for (int s = 128; s > 0; s >>= 1) {
        if (threadIdx.x < s) red[threadIdx.x] += red[threadIdx.x + s];
        __syncthreads();
    }
    float r = red[0];
    __syncthreads();
    return r;
}

// split-K GEMM: kchunk = 256, ksplit = K/256; partials f32 [ksplit][nz*64][N]
__device__ void gemm_phase(int bid, const GSeg* segs, const u16* Wt,
                           int K, int N, int nz, float* part) {
    const int ksplit = K >> 8;
    const int ntiles = N >> 6;
    const int total = ntiles * nz * ksplit;
    const int lane = threadIdx.x & 63;
    const int wave = threadIdx.x >> 6;
    const int l16 = lane & 15, quad = lane >> 4;
    for (int id = bid; id < total; id += NBLK) {
        const int kc = id % ksplit;
        const int tz = id / ksplit;
        const int ntile = tz % ntiles;
        const int z = tz / ntiles;
        const int n = ntile * 64 + wave * 16 + l16;
        const int k0 = kc << 8;
        const GSeg sg = segs[k0 >> 9];
        const int koff = k0 & 511;
        const u16* ab = sg.p + (long)z * sg.zs + koff + quad * 8;
        const u16* a0 = ab + (long)l16 * sg.rs;
        const u16* a1 = a0 + (long)16 * sg.rs;
        const u16* a2 = a0 + (long)32 * sg.rs;
        const u16* a3 = a0 + (long)48 * sg.rs;
        const u16* wp = Wt + (long)n * K + k0 + quad * 8;
        f32x4 acc0 = {0.f, 0.f, 0.f, 0.f};
        f32x4 acc1 = acc0, acc2 = acc0, acc3 = acc0;
        for (int k = 0; k < 256; k += 32) {
            short8 av0 = *(const short8*)(a0 + k);
            short8 av1 = *(const short8*)(a1 + k);
            short8 av2 = *(const short8*)(a2 + k);
            short8 av3 = *(const short8*)(a3 + k);
            short8 bv = ntldv(wp + k);
            acc0 = __builtin_amdgcn_mfma_f32_16x16x32_bf16(av0, bv, acc0, 0, 0, 0);
            acc1 = __builtin_amdgcn_mfma_f32_16x16x32_bf16(av1, bv, acc1, 0, 0, 0);
            acc2 = __builtin_amdgcn_mfma_f32_16x16x32_bf16(av2, bv, acc2, 0, 0, 0);
            acc3 = __builtin_amdgcn_mfma_f32_16x16x32_bf16(av3, bv, acc3, 0, 0, 0);
        }
        float* pr = part + (long)kc * (nz * 64 * N) + (long)(z * 64) * N + n;
        f32x4 accs[4] = {acc0, acc1, acc2, acc3};
#pragma unroll
        for (int mt = 0; mt < 4; ++mt)
#pragma unroll
            for (int r = 0; r < 4; ++r)
                ntstf(pr + (long)(mt * 16 + quad * 4 + r) * N, accs[mt][r]);
    }
}

// reduce ksplit partials + bias + relu -> bf16 (N fixed 2048, M=64)
__device__ void reduce_phase(int bid, const float* part, int ksplit,
                             const float* bias, u16* outb) {
    const int MN = 64 * 2048;
    for (int i = bid * 256 + threadIdx.x; i < MN; i += NBLK * 256) {
        float s = bias[i & 2047];
        for (int kc = 0; kc < ksplit; ++kc) s += ntldf(part + (long)kc * MN + i);
        ntstu(outb + i, f2b(s > 0.f ? s : 0.f));
    }
}

// gate with folded partial-reduce; out rows stride NS*DD
__device__ void gate_phase(int bid, SH& sh, const float* part, int ksplit, int N, int W1,
                           const float* bias, const float* gw, const float* gb,
                           const float* s0, int s0_rs, const float* s1, int s1_rs,
                           float* out_f, u16* out_b) {
    if (bid >= BB) return;
    const int b = bid, tid = threadIdx.x;
    const int MN = 64 * N;
    float s = 0.f, ss = 0.f;
    for (int j = tid; j < N; j += 256) {
        float v = bias[j];
        for (int kc = 0; kc < ksplit; ++kc) v += ntldf(part + (long)kc * MN + (long)b * N + j);
        sh.arow[j] = v;
        if (j < W1) { s += v; ss += v * v; }
    }
    float tot = block_sum(s, sh.red);
    float tot2 = block_sum(ss, sh.red);
    float mu = tot / (float)W1;
    float var = tot2 / (float)W1 - mu * mu;
    float inv = rsqrtf(var + LN_EPS);

    float s2 = 0.f, ss2 = 0.f;
    for (int d = tid; d < DD; d += 256) {
        float g0 = sigm((sh.arow[d] - mu) * inv * gw[d] + gb[d]);
        float val = g0 * s0[(long)b * s0_rs + d];
        if (s1) {
            float g1 = sigm((sh.arow[DD + d] - mu) * inv * gw[DD + d] + gb[DD + d]);
            val += g1 * s1[(long)b * s1_rs + d];
        }
        float gc = sigm((sh.arow[W1 - DD + d] - mu) * inv * gw[W1 - DD + d] + gb[W1 - DD + d]);
        val += gc * sh.arow[W1 + d];
        sh.u[d] = val;
        s2 += val; ss2 += val * val;
    }
    float t2 = block_sum(s2, sh.red);
    float t22 = block_sum(ss2, sh.red);
    float mu2 = t2 / (float)DD;
    float var2 = t22 / (float)DD - mu2 * mu2;
    float inv2 = rsqrtf(var2 + LN_EPS);
    for (int d = tid; d < DD; d += 256) {
        float v = (sh.u[d] - mu2) * inv2;
        long o = (long)b * (NS * DD) + d;
        out_f[o] = v;
        out_b[o] = f2b(v);
    }
}

// pbm with folded gd-partial reduce + leaky
__device__ void pbm_phase(int bid, SH& sh, const float* part,
                          const float* bd1, const float* Wd2, const float* bd2,
                          const float* cand_f, float* m_f, u16* m_b, float* chl_f,
                          float* pp, void* out, long ph_base, int isf) {
    if (bid >= BB) return;
    const int b = bid, tid = threadIdx.x;
    const int MN = 192 * 512;
    float dot[3];
    for (int n = 0; n < 3; ++n) {
        float sacc = 0.f;
        for (int k = tid; k < 512; k += 256) {
            float h = bd1[k];
            for (int kc = 0; kc < 8; ++kc)
                h += ntldf(part + (long)kc * MN + (long)(n * 64 + b) * 512 + k);
            h = h > 0.f ? h : 0.3f * h;
            sacc += h * Wd2[k];
        }
        dot[n] = block_sum(sacc, sh.red);
    }
    if (tid == 0) {
        float bd = bd2[0];
        float b0 = sigm(dot[0] + bd), b1 = sigm(dot[1] + bd), b2 = sigm(dot[2] + bd);
        float ph0 = (1.f - b2) * (1.f - b1) * (1.f - b0);
        float ph1 = b0 * (1.f - b2) * (1.f - b1);
        float ph2 = b1 * (1.f - b2);
        float ph3 = b2;
        float sum = fmaxf(ph1 + ph2 + ph3, 1e-30f);
        float p0 = ph1 / sum, p1 = ph2 / sum, p2 = ph3 / sum;
        sh.sl[0] = p0 + p1 + p2; sh.sl[1] = p1 + p2; sh.sl[2] = p2;
        pp[b * 4 + 0] = p0; pp[b * 4 + 1] = p1;
        pp[b * 4 + 2] = p2; pp[b * 4 + 3] = ph0;
        long ob = ph_base + (long)b * (TT * (NS + 1));
        stout(out, ob + 0, ph0, isf);
        stout(out, ob + 1, ph1, isf);
        stout(out, ob + 2, ph2, isf);
        stout(out, ob + 3, ph3, isf);
    }
    __syncthreads();
    for (int idx = tid; idx < NS * DD; idx += 256) {
        int n = idx >> 9, d = idx & (DD - 1);
        float r = sh.sl[n];
        long o = (long)b * NS * DD + idx;
        float v = m_f[o] * (1.f - r) + cand_f[o] * r;
        m_f[o] = v;
        m_b[o] = f2b(v);
        if (n == 0) chl_f[(long)b * NS * DD + d] = v;
    }
}

__device__ void final_phase(int bid, SH& sh, const float* chl, const float* pp,
                            const float* task, const float* inp,
                            const float* Wa, const float* ba,
                            void* out, long o_base, int isf) {
    if (bid >= BB) return;
    const int b = bid, tid = threadIdx.x;
    const float* pb = pp + b * 4;
    const float* c = chl + (long)b * NS * DD;
    for (int d = tid; d < DD; d += 256) {
        sh.arow[d] = pb[0] * c[d] + pb[1] * c[DD + d] + pb[2] * c[2 * DD + d];
        sh.arow[DD + d] = task[b * DD + d];
        sh.arow[2 * DD + d] = inp[(long)b * (TT * DD) + d];
    }
    __syncthreads();
    if (tid < 240) {
        int a = tid >> 4, kk = tid & 15;
        float sacc = 0.f;
        for (int k = kk; k < 3 * DD; k += 16) sacc += sh.arow[k] * Wa[k * (ACT - 1) + a];
        sacc += __shfl_down(sacc, 8);
        sacc += __shfl_down(sacc, 4);
        sacc += __shfl_down(sacc, 2);
        sacc += __shfl_down(sacc, 1);
        if (kk == 0) sh.sl[a] = sacc + ba[a];
    }
    __syncthreads();
    if (tid == 0) {
        float mx = -1e30f;
        for (int a = 0; a < ACT - 1; ++a) mx = fmaxf(mx, sh.sl[a]);
        float se = 0.f;
        for (int a = 0; a < ACT - 1; ++a) se += expf(sh.sl[a] - mx);
        float lse = logf(se);
        float pe = pb[3];
        pe = fminf(fmaxf(pe, 1e-6f), 1.f - 1e-6f);
        float l1me = logf(1.f - pe);
        long ob = o_base + (long)b * (TT * ACT);
        for (int a = 0; a < ACT - 1; ++a) {
            float lg = sh.sl[a] - mx - lse + l1me;
            int pos = (a < DONE) ? a : a + 1;
            stout(out, ob + pos, lg, isf);
        }
        stout(out, ob + DONE, logf(pe), isf);
    }
}

struct PArgs {
    const u16 *comW1t, *comW2t, *decW1t, *decW2t, *Wd1t;
    const float *b_comb1, *b_comb2, *g_com, *beta_com;
    const float *b_decb1, *b_decb2, *g_dec, *beta_dec;
    const float *b_bd1, *w_Wd2, *b_bd2, *w_Wa, *b_ba;
    const u16 *obs_b_inp; const float *obs_f_inp;
    const u16 *task_b; const float *task_f;
    u16 *m_b; float *m_f; u16 *cand_b; float *cand_f;
    u16 *chl_b; float *chl_f; u16 *a1_b;
    float *part; float *pp;
    void *out; const int *flag;
    int *bar;
};

__global__ __launch_bounds__(256, 1) void persist_k(PArgs A) {
    __shared__ SH sh;
    const int bid = blockIdx.x;
    int* cnt = A.bar;
    int* gen = A.bar + 64;
    const int isf = *A.flag;

    for (int t = 0; t < TT; ++t) {
        const u16* inpb = A.obs_b_inp + t * DD;
        const float* inpf = A.obs_f_inp + t * DD;

        for (int ii = NS - 1; ii >= 0; --ii) {
            {
                GSeg segs[4] = {
                    { ii == NS - 1 ? inpb : A.cand_b + (ii + 1) * DD,
                      ii == NS - 1 ? TT * DD : NS * DD, 0 },
                    { A.m_b + ii * DD, NS * DD, 0 },
                    { inpb, TT * DD, 0 },
                    { A.task_b, DD, 0 } };
                gemm_phase(bid, segs, A.comW1t + (long)ii * 2048 * 2048, 2048, 2048, 1, A.part);
            }
            gbar(cnt, gen);
            reduce_phase(bid, A.part, 8, A.b_comb1 + ii * 2048, A.a1_b);
            gbar(cnt, gen);
            {
                GSeg segs[4] = { {A.a1_b, 2048, 0}, {A.a1_b + 512, 2048, 0},
                                 {A.a1_b + 1024, 2048, 0}, {A.a1_b + 1536, 2048, 0} };
                gemm_phase(bid, segs, A.comW2t + (long)ii * 2048 * 2048, 2048, 2048, 1, A.part);
            }
            gbar(cnt, gen);
            gate_phase(bid, sh, A.part, 8, 2048, 1536,
                       A.b_comb2 + ii * 2048, A.g_com + ii * 1536, A.beta_com + ii * 1536,
                       ii == NS - 1 ? inpf : A.cand_f + (ii + 1) * DD,
                       ii == NS - 1 ? TT * DD : NS * DD,
                       A.m_f + ii * DD, NS * DD,
                       A.cand_f + ii * DD, A.cand_b + ii * DD);
            gbar(cnt, gen);
        }

        {
            GSeg segs[4] = { {inpb, TT * DD, 0}, {A.task_b, DD, 0},
                             {A.m_b, NS * DD, DD}, {A.cand_b, NS * DD, DD} };
            gemm_phase(bid, segs, A.Wd1t, 2048, 512, 3, A.part);
        }
        gbar(cnt, gen);
        pbm_phase(bid, sh, A.part, A.b_bd1, A.w_Wd2, A.b_bd2, A.cand_f,
                  A.m_f, A.m_b, A.chl_f, A.pp, A.out,
                  (long)BB * TT * ACT + (long)t * (NS + 1), isf);
        gbar(cnt, gen);

        for (int j = 0; j < 2; ++j) {
            {
                GSeg segs[3] = { { j == 0 ? A.m_b : A.chl_b + DD, NS * DD, 0 },
                                 { inpb, TT * DD, 0 },
                                 { A.task_b, DD, 0 } };
                gemm_phase(bid, segs, A.decW1t + (long)j * 2048 * 1536, 1536, 2048, 1, A.part);
            }
            gbar(cnt, gen);
            reduce_phase(bid, A.part, 6, A.b_decb1 + j * 2048, A.a1_b);
            gbar(cnt, gen);
            {
                GSeg segs[4] = { {A.a1_b, 2048, 0}, {A.a1_b + 512, 2048, 0},
                                 {A.a1_b + 1024, 2048, 0}, {A.a1_b + 1536, 2048, 0} };
                gemm_phase(bid, segs, A.decW2t + (long)j * 1536 * 2048, 2048, 1536, 1, A.part);
            }
            gbar(cnt, gen);
            gate_phase(bid, sh, A.part, 8, 1536, 1024,
                       A.b_decb2 + j * 1536, A.g_dec + j * 1024, A.beta_dec + j * 1024,
                       j == 0 ? A.m_f : A.chl_f + DD, NS * DD,
                       nullptr, 0,
                       A.chl_f + (j + 1) * DD, A.chl_b + (j + 1) * DD);
            gbar(cnt, gen);
        }

        final_phase(bid, sh, A.chl_f, A.pp, A.task_f, inpf, A.w_Wa, A.b_ba,
                    A.out, (long)t * ACT, isf);
        gbar(cnt, gen);
    }
}

// ---------------- host ----------------
extern "C" void kernel_launch(void* const* d_in, const int* in_sizes, int n_in,
                              void* d_out, int out_size, void* d_ws, size_t ws_size,
                              hipStream_t stream) {
    const void* obs = d_in[0];
    const int* env = (const int*)d_in[1];
    const void* prevm = d_in[2];
    const void* emb = d_in[4];
    const void* Wobs = d_in[5];
    const void* bobs = d_in[6];
    const void* comW1 = d_in[7];
    const void* comb1 = d_in[8];
    const void* comW2 = d_in[9];
    const void* comb2 = d_in[10];
    const void* comg = d_in[11];
    const void* combeta = d_in[12];
    const void* decW1 = d_in[13];
    const void* decb1 = d_in[14];
    const void* decW2 = d_in[15];
    const void* decb2 = d_in[16];
    const void* decg = d_in[17];
    const void* decbeta = d_in[18];
    const void* Wd1 = d_in[19];
    const void* bd1 = d_in[20];
    const void* Wd2 = d_in[21];
    const void* bd2 = d_in[22];
    const void* Wa = d_in[23];
    const void* ba = d_in[24];

    char* p = (char*)d_ws;
    auto carve = [&](size_t bytes) -> char* {
        char* r = p;
        p += (bytes + 255) & ~(size_t)255;
        return r;
    };
    int* flag = (int*)carve(256);
    int* bar = (int*)carve(512);
    u16* comW1t = (u16*)carve(3ull * 2048 * 2048 * 2);
    u16* comW2t = (u16*)carve(3ull * 2048 * 2048 * 2);
    u16* decW1t = (u16*)carve(2ull * 2048 * 1536 * 2);
    u16* decW2t = (u16*)carve(2ull * 1536 * 2048 * 2);
    u16* Wd1t = (u16*)carve(512ull * 2048 * 2);
    u16* Wobst = (u16*)carve(512ull * 128 * 2);
    u16* obs_b = (u16*)carve((size_t)BB * TT * OBSD * 2);
    float* obs_inp_f = (float*)carve((size_t)BB * TT * DD * 4);
    u16* obs_inp_b = (u16*)carve((size_t)BB * TT * DD * 2);
    float* task_f = (float*)carve((size_t)BB * DD * 4);
    u16* task_b = (u16*)carve((size_t)BB * DD * 2);
    float* m_f = (float*)carve((size_t)BB * NS * DD * 4);
    u16* m_b = (u16*)carve((size_t)BB * NS * DD * 2);
    float* cand_f = (float*)carve((size_t)BB * NS * DD * 4);
    u16* cand_b = (u16*)carve((size_t)BB * NS * DD * 2);
    float* chl_f = (float*)carve((size_t)BB * NS * DD * 4);
    u16* chl_b = (u16*)carve((size_t)BB * NS * DD * 2);
    u16* a1_b = (u16*)carve((size_t)BB * 2048 * 2);
    float* part = (float*)carve(8ull * 64 * 2048 * 4);
    float* pp = (float*)carve((size_t)BB * 4 * 4);
    float* st_bobs = (float*)carve(512 * 4);
    float* st_comb1 = (float*)carve(3 * 2048 * 4);
    float* st_comb2 = (float*)carve(3 * 2048 * 4);
    float* st_comg = (float*)carve(3 * 1536 * 4);
    float* st_combeta = (float*)carve(3 * 1536 * 4);
    float* st_decb1 = (float*)carve(2 * 2048 * 4);
    float* st_decb2 = (float*)carve(2 * 1536 * 4);
    float* st_decg = (float*)carve(2 * 1024 * 4);
    float* st_decbeta = (float*)carve(2 * 1024 * 4);
    float* st_bd1 = (float*)carve(512 * 4);
    float* st_Wd2 = (float*)carve(512 * 4);
    float* st_bd2 = (float*)carve(256);
    float* st_Wa = (float*)carve(1536 * 15 * 4);
    float* st_ba = (float*)carve(15 * 4);

    dim3 blk(256);

    detect_k<<<dim3(1), dim3(64), 0, stream>>>(Wobs, flag, bar);

    {
        StageArgs sa{};
        const void* srcs[14] = {bobs, comb1, comb2, comg, combeta, decb1, decb2,
                                decg, decbeta, bd1, Wd2, bd2, Wa, ba};
        float* dsts[14] = {st_bobs, st_comb1, st_comb2, st_comg, st_combeta, st_decb1,
                           st_decb2, st_decg, st_decbeta, st_bd1, st_Wd2, st_bd2, st_Wa, st_ba};
        int ns[14] = {512, 6144, 6144, 4608, 4608, 4096, 3072, 2048, 2048, 512, 512, 1, 23040, 15};
        for (int i = 0; i < 14; ++i) { sa.src[i] = srcs[i]; sa.dst[i] = dsts[i]; sa.n[i] = ns[i]; }
        sa.flag = flag;
        stage_k<<<dim3(90, 14, 1), blk, 0, stream>>>(sa);
    }

    transpose_k<<<dim3(16, 4, 1), blk, 0, stream>>>(Wobs, Wobst, 128, 512, flag);
    transpose_k<<<dim3(64, 64, 3), blk, 0, stream>>>(comW1, comW1t, 2048, 2048, flag);
    transpose_k<<<dim3(64, 64, 3), blk, 0, stream>>>(comW2, comW2t, 2048, 2048, flag);
    transpose_k<<<dim3(64, 48, 2), blk, 0, stream>>>(decW1, decW1t, 1536, 2048, flag);
    transpose_k<<<dim3(48, 64, 2), blk, 0, stream>>>(decW2, decW2t, 2048, 1536, flag);
    transpose_k<<<dim3(16, 64, 1), blk, 0, stream>>>(Wd1, Wd1t, 2048, 512, flag);
    convb_k<<<dim3((BB * TT * OBSD + 255) / 256), blk, 0, stream>>>(obs, obs_b, BB * TT * OBSD, flag);
    init_k<<<dim3(BB), blk, 0, stream>>>(emb, env, prevm, task_f, task_b, m_b, m_f, flag);
    obsgemm_k<<<dim3(DD / 64, (BB * TT) / 64, 1), blk, 0, stream>>>(obs_b, Wobst, st_bobs,
                                                                    obs_inp_f, obs_inp_b);

    PArgs pa{};
    pa.comW1t = comW1t; pa.comW2t = comW2t; pa.decW1t = decW1t; pa.decW2t = decW2t; pa.Wd1t = Wd1t;
    pa.b_comb1 = st_comb1; pa.b_comb2 = st_comb2; pa.g_com = st_comg; pa.beta_com = st_combeta;
    pa.b_decb1 = st_decb1; pa.b_decb2 = st_decb2; pa.g_dec = st_decg; pa.beta_dec = st_decbeta;
    pa.b_bd1 = st_bd1; pa.w_Wd2 = st_Wd2; pa.b_bd2 = st_bd2; pa.w_Wa = st_Wa; pa.b_ba = st_ba;
    pa.obs_b_inp = obs_inp_b; pa.obs_f_inp = obs_inp_f;
    pa.task_b = task_b; pa.task_f = task_f;
    pa.m_b = m_b; pa.m_f = m_f; pa.cand_b = cand_b; pa.cand_f = cand_f;
    pa.chl_b = chl_b; pa.chl_f = chl_f; pa.a1_b = a1_b;
    pa.part = part; pa.pp = pp;
    pa.out = d_out; pa.flag = flag;
    pa.bar = bar;

    persist_k<<<dim3(NBLK), dim3(256), 0, stream>>>(pa);
}

// Round 6
// 16336.362 us; speedup vs baseline: 4.6045x; 1.5033x over previous
//
#include <hip/hip_runtime.h>
#include <stdint.h>

#define BB 64
#define TT 64
#define OBSD 128
#define DD 512
#define NS 3
#define ACT 16
#define DONE 5
#define LN_EPS 1e-3f
#define NBLK 256

typedef unsigned short u16;
typedef unsigned int u32;
typedef unsigned long long u64;
typedef __attribute__((ext_vector_type(8))) short short8;
typedef __attribute__((ext_vector_type(4))) float f32x4;

__device__ __forceinline__ float b2f(u16 u) {
    return __uint_as_float(((unsigned int)u) << 16);
}
__device__ __forceinline__ u16 f2b(float f) {
    unsigned int x = __float_as_uint(f);
    unsigned int r = x + 0x7fffu + ((x >> 16) & 1u);
    return (u16)(r >> 16);
}
__device__ __forceinline__ float sigm(float x) { return 1.f / (1.f + expf(-x)); }
__device__ __forceinline__ float ldin(const void* p, long i, int isf) {
    return isf ? ((const float*)p)[i] : b2f(((const u16*)p)[i]);
}
__device__ __forceinline__ void stout(void* p, long i, float v, int isf) {
    if (isf) ((float*)p)[i] = v; else ((u16*)p)[i] = f2b(v);
}

// ---- LLC-coherent (L1/L2-bypassing) accessors for cross-block data ----
__device__ __forceinline__ float atldf(const float* p) {
    return __hip_atomic_load(p, __ATOMIC_RELAXED, __HIP_MEMORY_SCOPE_AGENT);
}
__device__ __forceinline__ void atstf(float* p, float v) {
    __hip_atomic_store(p, v, __ATOMIC_RELAXED, __HIP_MEMORY_SCOPE_AGENT);
}
__device__ __forceinline__ u64 atldq(const void* p) {
    return __hip_atomic_load((const u64*)p, __ATOMIC_RELAXED, __HIP_MEMORY_SCOPE_AGENT);
}
__device__ __forceinline__ void atstq(void* p, u64 v) {
    __hip_atomic_store((u64*)p, v, __ATOMIC_RELAXED, __HIP_MEMORY_SCOPE_AGENT);
}
__device__ __forceinline__ void atstd(void* p, u32 v) {
    __hip_atomic_store((u32*)p, v, __ATOMIC_RELAXED, __HIP_MEMORY_SCOPE_AGENT);
}
// 16B bf16 A-fragment load via two coherent 8B loads
__device__ __forceinline__ short8 atld8h(const u16* p) {
    union { u64 q[2]; short8 v; } u;
    u.q[0] = atldq(p);
    u.q[1] = atldq(p + 4);
    return u.v;
}

// ---------------- dtype detector + barrier init ----------------
__global__ void detect_k(const void* probe, int* flag, int* bar) {
    if (threadIdx.x == 0 && blockIdx.x == 0) {
        const u16* u = (const u16*)probe;
        int nz = 0, npl = 0;
        for (int j = 0; j < 128; ++j) {
            u16 v = u[2 * j];
            if (v == 0) { nz++; continue; }
            int e = (v >> 7) & 0xff;
            if (e >= 0x70 && e <= 0x88) npl++;
        }
        int nonzero = 128 - nz;
        *flag = (npl * 2 > nonzero) ? 0 : 1;  // 0 = bf16, 1 = f32
        bar[0] = 0;   // count
        bar[64] = 0;  // generation
    }
}

// ---------------- stage small params -> f32 ws ----------------
struct StageArgs { const void* src[16]; float* dst[16]; int n[16]; const int* flag; };
__global__ __launch_bounds__(256) void stage_k(StageArgs s) {
    int isf = *s.flag;
    int z = blockIdx.y;
    int i = blockIdx.x * 256 + threadIdx.x;
    if (s.src[z] && i < s.n[z]) s.dst[z][i] = ldin(s.src[z], i, isf);
}

// ---------------- elementwise convert -> bf16 ----------------
__global__ __launch_bounds__(256) void convb_k(const void* src, u16* dst, int n, const int* flag) {
    int isf = *flag;
    int i = blockIdx.x * 256 + threadIdx.x;
    if (i < n) dst[i] = isf ? f2b(((const float*)src)[i]) : ((const u16*)src)[i];
}

// ---------------- transpose [K,N] -> bf16 [N,K] ----------------
__global__ __launch_bounds__(256) void transpose_k(const void* in, u16* out, int K, int N,
                                                   const int* flag) {
    __shared__ u16 tile[32][33];
    int isf = *flag;
    long zoff = (long)blockIdx.z * K * N;
    int kb = blockIdx.y * 32, nb = blockIdx.x * 32;
    int tx = threadIdx.x & 31, ty = threadIdx.x >> 5;
    for (int r = ty; r < 32; r += 8) {
        long idx = zoff + (long)(kb + r) * N + nb + tx;
        tile[r][tx] = isf ? f2b(((const float*)in)[idx]) : ((const u16*)in)[idx];
    }
    __syncthreads();
    for (int r = ty; r < 32; r += 8)
        out[zoff + (long)(nb + r) * K + kb + tx] = tile[tx][r];
}

// ---------------- init: task_emb gather + m state ----------------
__global__ __launch_bounds__(256) void init_k(const void* emb, const int* env, const void* prevm,
                                              float* task_f, u16* task_b, u16* m_b, float* m_f,
                                              const int* flag) {
    int isf = *flag;
    int b = blockIdx.x, tid = threadIdx.x;
    int e = env[b];
    for (int j = tid; j < DD; j += 256) {
        float v = ldin(emb, (long)e * DD + j, isf);
        task_f[b * DD + j] = v;
        task_b[b * DD + j] = f2b(v);
    }
    for (int j = tid; j < NS * DD; j += 256) {
        float v = ldin(prevm, (long)b * NS * DD + j, isf);
        m_b[b * NS * DD + j] = f2b(v);
        m_f[b * NS * DD + j] = v;
    }
}

// ---------------- obs GEMM (standalone, big grid) ----------------
__global__ __launch_bounds__(256) void obsgemm_k(const u16* __restrict__ X, const u16* __restrict__ Wt,
                                                 const float* __restrict__ bias,
                                                 float* __restrict__ yf, u16* __restrict__ yb) {
    const int lane = threadIdx.x & 63;
    const int wave = threadIdx.x >> 6;
    const int l16 = lane & 15;
    const int quad = lane >> 4;
    const int n = blockIdx.x * 64 + wave * 16 + l16;
    const int m_base = blockIdx.y * 64;

    f32x4 acc0 = {0.f, 0.f, 0.f, 0.f};
    f32x4 acc1 = acc0, acc2 = acc0, acc3 = acc0;
    const u16* a0 = X + (long)(m_base + l16) * OBSD + quad * 8;
    const u16* a1 = a0 + (long)16 * OBSD;
    const u16* a2 = a0 + (long)32 * OBSD;
    const u16* a3 = a0 + (long)48 * OBSD;
    const u16* wp = Wt + (long)n * OBSD + quad * 8;
    for (int k = 0; k < OBSD; k += 32) {
        short8 av0 = *(const short8*)(a0 + k);
        short8 av1 = *(const short8*)(a1 + k);
        short8 av2 = *(const short8*)(a2 + k);
        short8 av3 = *(const short8*)(a3 + k);
        short8 bv = *(const short8*)(wp + k);
        acc0 = __builtin_amdgcn_mfma_f32_16x16x32_bf16(av0, bv, acc0, 0, 0, 0);
        acc1 = __builtin_amdgcn_mfma_f32_16x16x32_bf16(av1, bv, acc1, 0, 0, 0);
        acc2 = __builtin_amdgcn_mfma_f32_16x16x32_bf16(av2, bv, acc2, 0, 0, 0);
        acc3 = __builtin_amdgcn_mfma_f32_16x16x32_bf16(av3, bv, acc3, 0, 0, 0);
    }
    float bb = bias[n];
    f32x4 accs[4] = {acc0, acc1, acc2, acc3};
#pragma unroll
    for (int mt = 0; mt < 4; ++mt)
#pragma unroll
        for (int r = 0; r < 4; ++r) {
            int m = m_base + mt * 16 + quad * 4 + r;
            float v = accs[mt][r] + bb;
            yf[(long)m * DD + n] = v;
            yb[(long)m * DD + n] = f2b(v);
        }
}

// ================= persistent kernel (plain launch, 1 block/CU) =================
struct GSeg { const u16* p; int rs; int zs; };
struct SH { float arow[2048]; float red[256]; float u[512]; float sl[16]; };

// No agent fences: all cross-block data moves through LLC-coherent atomics,
// so the barrier needs only arrival + spin. __syncthreads drains each wave's
// outstanding stores; workgroup fences pin compiler ordering.
__device__ __forceinline__ void gbar(int* cnt, int* gen) {
    __syncthreads();
    if (threadIdx.x == 0) {
        __builtin_amdgcn_fence(__ATOMIC_RELEASE, "workgroup");
        __builtin_amdgcn_s_waitcnt(0);
        int g0 = __hip_atomic_load(gen, __ATOMIC_RELAXED, __HIP_MEMORY_SCOPE_AGENT);
        if (__hip_atomic_fetch_add(cnt, 1, __ATOMIC_RELAXED, __HIP_MEMORY_SCOPE_AGENT) == NBLK - 1) {
            __hip_atomic_store(cnt, 0, __ATOMIC_RELAXED, __HIP_MEMORY_SCOPE_AGENT);
            __hip_atomic_store(gen, g0 + 1, __ATOMIC_RELAXED, __HIP_MEMORY_SCOPE_AGENT);
        } else {
            while (__hip_atomic_load(gen, __ATOMIC_RELAXED, __HIP_MEMORY_SCOPE_AGENT) == g0)
                __builtin_amdgcn_s_sleep(2);
        }
        __builtin_amdgcn_fence(__ATOMIC_ACQUIRE, "workgroup");
    }
    __syncthreads();
}

__device__ __forceinline__ float block_sum(float v, float* red) {
    red[threadIdx.x] = v;
    __syncthreads();
    for (int s = 128; s > 0; s >>= 1) {
        if (threadIdx.x < s) red[threadIdx.x] += red[threadIdx.x + s];
        __syncthreads();
    }
    float r = red[0];
    __syncthreads();
    return r;
}

// split-K GEMM: kchunk = 256, ksplit = K/256; partials f32 [ksplit][nz*64][N]
// A-operands: LLC-coherent atomic loads (cross-block data). W: plain cached.
__device__ void gemm_phase(int bid, const GSeg* segs, const u16* Wt,
                           int K, int N, int nz, float* part) {
    const int ksplit = K >> 8;
    const int ntiles = N >> 6;
    const int total = ntiles * nz * ksplit;
    const int lane = threadIdx.x & 63;
    const int wave = threadIdx.x >> 6;
    const int l16 = lane & 15, quad = lane >> 4;
    for (int id = bid; id < total; id += NBLK) {
        const int kc = id % ksplit;
        const int tz = id / ksplit;
        const int ntile = tz % ntiles;
        const int z = tz / ntiles;
        const int n = ntile * 64 + wave * 16 + l16;
        const int k0 = kc << 8;
        const GSeg sg = segs[k0 >> 9];
        const int koff = k0 & 511;
        const u16* ab = sg.p + (long)z * sg.zs + koff + quad * 8;
        const u16* a0 = ab + (long)l16 * sg.rs;
        const u16* a1 = a0 + (long)16 * sg.rs;
        const u16* a2 = a0 + (long)32 * sg.rs;
        const u16* a3 = a0 + (long)48 * sg.rs;
        const u16* wp = Wt + (long)n * K + k0 + quad * 8;
        f32x4 acc0 = {0.f, 0.f, 0.f, 0.f};
        f32x4 acc1 = acc0, acc2 = acc0, acc3 = acc0;
        for (int k = 0; k < 256; k += 32) {
            short8 av0 = atld8h(a0 + k);
            short8 av1 = atld8h(a1 + k);
            short8 av2 = atld8h(a2 + k);
            short8 av3 = atld8h(a3 + k);
            short8 bv = *(const short8*)(wp + k);
            acc0 = __builtin_amdgcn_mfma_f32_16x16x32_bf16(av0, bv, acc0, 0, 0, 0);
            acc1 = __builtin_amdgcn_mfma_f32_16x16x32_bf16(av1, bv, acc1, 0, 0, 0);
            acc2 = __builtin_amdgcn_mfma_f32_16x16x32_bf16(av2, bv, acc2, 0, 0, 0);
            acc3 = __builtin_amdgcn_mfma_f32_16x16x32_bf16(av3, bv, acc3, 0, 0, 0);
        }
        float* pr = part + (long)kc * (nz * 64 * N) + (long)(z * 64) * N + n;
        f32x4 accs[4] = {acc0, acc1, acc2, acc3};
#pragma unroll
        for (int mt = 0; mt < 4; ++mt)
#pragma unroll
            for (int r = 0; r < 4; ++r)
                atstf(pr + (long)(mt * 16 + quad * 4 + r) * N, accs[mt][r]);
    }
}

// reduce ksplit partials + bias + relu -> bf16 (N fixed 2048, M=64)
// exactly 2 elements per thread across the grid; packed u32 coherent store
__device__ void reduce_phase(int bid, const float* part, int ksplit,
                             const float* bias, u16* outb) {
    const int MN = 64 * 2048;
    const int i = (bid * 256 + threadIdx.x) * 2;  // MN/2 groups == NBLK*256
    float s0 = bias[i & 2047], s1 = bias[(i + 1) & 2047];
    for (int kc = 0; kc < ksplit; ++kc) {
        s0 += atldf(part + (long)kc * MN + i);
        s1 += atldf(part + (long)kc * MN + i + 1);
    }
    u32 pk = (u32)f2b(s0 > 0.f ? s0 : 0.f) | ((u32)f2b(s1 > 0.f ? s1 : 0.f) << 16);
    atstd(outb + i, pk);
}

// gate with folded partial-reduce; out rows stride NS*DD
__device__ void gate_phase(int bid, SH& sh, const float* part, int ksplit, int N, int W1,
                           const float* bias, const float* gw, const float* gb,
                           const float* s0, int s0_rs, const float* s1, int s1_rs,
                           float* out_f, u16* out_b) {
    if (bid >= BB) return;
    const int b = bid, tid = threadIdx.x;
    const int MN = 64 * N;
    float s = 0.f, ss = 0.f;
    for (int j = tid; j < N; j += 256) {
        float v = bias[j];
        for (int kc = 0; kc < ksplit; ++kc) v += atldf(part + (long)kc * MN + (long)b * N + j);
        sh.arow[j] = v;
        if (j < W1) { s += v; ss += v * v; }
    }
    float tot = block_sum(s, sh.red);
    float tot2 = block_sum(ss, sh.red);
    float mu = tot / (float)W1;
    float var = tot2 / (float)W1 - mu * mu;
    float inv = rsqrtf(var + LN_EPS);

    const int d0 = tid * 2;
    float s2 = 0.f, ss2 = 0.f;
#pragma unroll
    for (int k = 0; k < 2; ++k) {
        int d = d0 + k;
        float g0 = sigm((sh.arow[d] - mu) * inv * gw[d] + gb[d]);
        float val = g0 * atldf(s0 + (long)b * s0_rs + d);
        if (s1) {
            float g1 = sigm((sh.arow[DD + d] - mu) * inv * gw[DD + d] + gb[DD + d]);
            val += g1 * atldf(s1 + (long)b * s1_rs + d);
        }
        float gc = sigm((sh.arow[W1 - DD + d] - mu) * inv * gw[W1 - DD + d] + gb[W1 - DD + d]);
        val += gc * sh.arow[W1 + d];
        sh.u[d] = val;
        s2 += val; ss2 += val * val;
    }
    float t2 = block_sum(s2, sh.red);
    float t22 = block_sum(ss2, sh.red);
    float mu2 = t2 / (float)DD;
    float var2 = t22 / (float)DD - mu2 * mu2;
    float inv2 = rsqrtf(var2 + LN_EPS);
    float v0 = (sh.u[d0] - mu2) * inv2;
    float v1 = (sh.u[d0 + 1] - mu2) * inv2;
    long o = (long)b * (NS * DD) + d0;
    atstf(out_f + o, v0);
    atstf(out_f + o + 1, v1);
    atstd(out_b + o, (u32)f2b(v0) | ((u32)f2b(v1) << 16));
}

// pbm with folded gd-partial reduce + leaky
__device__ void pbm_phase(int bid, SH& sh, const float* part,
                          const float* bd1, const float* Wd2, const float* bd2,
                          const float* cand_f, float* m_f, u16* m_b, float* chl_f,
                          float* pp, void* out, long ph_base, int isf) {
    if (bid >= BB) return;
    const int b = bid, tid = threadIdx.x;
    const int MN = 192 * 512;
    float dot[3];
    for (int n = 0; n < 3; ++n) {
        float sacc = 0.f;
        for (int k = tid; k < 512; k += 256) {
            float h = bd1[k];
            for (int kc = 0; kc < 8; ++kc)
                h += atldf(part + (long)kc * MN + (long)(n * 64 + b) * 512 + k);
            h = h > 0.f ? h : 0.3f * h;
            sacc += h * Wd2[k];
        }
        dot[n] = block_sum(sacc, sh.red);
    }
    if (tid == 0) {
        float bd = bd2[0];
        float b0 = sigm(dot[0] + bd), b1 = sigm(dot[1] + bd), b2 = sigm(dot[2] + bd);
        float ph0 = (1.f - b2) * (1.f - b1) * (1.f - b0);
        float ph1 = b0 * (1.f - b2) * (1.f - b1);
        float ph2 = b1 * (1.f - b2);
        float ph3 = b2;
        float sum = fmaxf(ph1 + ph2 + ph3, 1e-30f);
        float p0 = ph1 / sum, p1 = ph2 / sum, p2 = ph3 / sum;
        sh.sl[0] = p0 + p1 + p2; sh.sl[1] = p1 + p2; sh.sl[2] = p2;
        atstf(pp + b * 4 + 0, p0); atstf(pp + b * 4 + 1, p1);
        atstf(pp + b * 4 + 2, p2); atstf(pp + b * 4 + 3, ph0);
        long ob = ph_base + (long)b * (TT * (NS + 1));
        stout(out, ob + 0, ph0, isf);
        stout(out, ob + 1, ph1, isf);
        stout(out, ob + 2, ph2, isf);
        stout(out, ob + 3, ph3, isf);
    }
    __syncthreads();
    if (tid < 192) {
        const int idx0 = tid * 8;
        u16 mb[8];
#pragma unroll
        for (int k = 0; k < 8; ++k) {
            int idx = idx0 + k;
            int n = idx >> 9, d = idx & (DD - 1);
            float r = sh.sl[n];
            long o = (long)b * (NS * DD) + idx;
            float v = atldf(m_f + o) * (1.f - r) + atldf(cand_f + o) * r;
            atstf(m_f + o, v);
            mb[k] = f2b(v);
            if (n == 0) atstf(chl_f + (long)b * (NS * DD) + d, v);
        }
        u64 q0 = (u64)mb[0] | ((u64)mb[1] << 16) | ((u64)mb[2] << 32) | ((u64)mb[3] << 48);
        u64 q1 = (u64)mb[4] | ((u64)mb[5] << 16) | ((u64)mb[6] << 32) | ((u64)mb[7] << 48);
        atstq(m_b + (long)b * (NS * DD) + idx0, q0);
        atstq(m_b + (long)b * (NS * DD) + idx0 + 4, q1);
    }
}

__device__ void final_phase(int bid, SH& sh, const float* chl, const float* pp,
                            const float* task, const float* inp,
                            const float* Wa, const float* ba,
                            void* out, long o_base, int isf) {
    if (bid >= BB) return;
    const int b = bid, tid = threadIdx.x;
    float pb0 = atldf(pp + b * 4 + 0), pb1 = atldf(pp + b * 4 + 1);
    float pb2 = atldf(pp + b * 4 + 2), pb3 = atldf(pp + b * 4 + 3);
    const float* c = chl + (long)b * NS * DD;
    for (int d = tid; d < DD; d += 256) {
        sh.arow[d] = pb0 * atldf(c + d) + pb1 * atldf(c + DD + d) + pb2 * atldf(c + 2 * DD + d);
        sh.arow[DD + d] = task[b * DD + d];
        sh.arow[2 * DD + d] = inp[(long)b * (TT * DD) + d];
    }
    __syncthreads();
    if (tid < 240) {
        int a = tid >> 4, kk = tid & 15;
        float sacc = 0.f;
        for (int k = kk; k < 3 * DD; k += 16) sacc += sh.arow[k] * Wa[k * (ACT - 1) + a];
        sacc += __shfl_down(sacc, 8);
        sacc += __shfl_down(sacc, 4);
        sacc += __shfl_down(sacc, 2);
        sacc += __shfl_down(sacc, 1);
        if (kk == 0) sh.sl[a] = sacc + ba[a];
    }
    __syncthreads();
    if (tid == 0) {
        float mx = -1e30f;
        for (int a = 0; a < ACT - 1; ++a) mx = fmaxf(mx, sh.sl[a]);
        float se = 0.f;
        for (int a = 0; a < ACT - 1; ++a) se += expf(sh.sl[a] - mx);
        float lse = logf(se);
        float pe = pb3;
        pe = fminf(fmaxf(pe, 1e-6f), 1.f - 1e-6f);
        float l1me = logf(1.f - pe);
        long ob = o_base + (long)b * (TT * ACT);
        for (int a = 0; a < ACT - 1; ++a) {
            float lg = sh.sl[a] - mx - lse + l1me;
            int pos = (a < DONE) ? a : a + 1;
            stout(out, ob + pos, lg, isf);
        }
        stout(out, ob + DONE, logf(pe), isf);
    }
}

struct PArgs {
    const u16 *comW1t, *comW2t, *decW1t, *decW2t, *Wd1t;
    const float *b_comb1, *b_comb2, *g_com, *beta_com;
    const float *b_decb1, *b_decb2, *g_dec, *beta_dec;
    const float *b_bd1, *w_Wd2, *b_bd2, *w_Wa, *b_ba;
    const u16 *obs_b_inp; const float *obs_f_inp;
    const u16 *task_b; const float *task_f;
    u16 *m_b; float *m_f; u16 *cand_b; float *cand_f;
    u16 *chl_b; float *chl_f; u16 *a1_b;
    float *part; float *pp;
    void *out; const int *flag;
    int *bar;
};

__global__ __launch_bounds__(256, 1) void persist_k(PArgs A) {
    __shared__ SH sh;
    const int bid = blockIdx.x;
    int* cnt = A.bar;
    int* gen = A.bar + 64;
    const int isf = *A.flag;

    for (int t = 0; t < TT; ++t) {
        const u16* inpb = A.obs_b_inp + t * DD;
        const float* inpf = A.obs_f_inp + t * DD;

        for (int ii = NS - 1; ii >= 0; --ii) {
            {
                GSeg segs[4] = {
                    { ii == NS - 1 ? inpb : A.cand_b + (ii + 1) * DD,
                      ii == NS - 1 ? TT * DD : NS * DD, 0 },
                    { A.m_b + ii * DD, NS * DD, 0 },
                    { inpb, TT * DD, 0 },
                    { A.task_b, DD, 0 } };
                gemm_phase(bid, segs, A.comW1t + (long)ii * 2048 * 2048, 2048, 2048, 1, A.part);
            }
            gbar(cnt, gen);
            reduce_phase(bid, A.part, 8, A.b_comb1 + ii * 2048, A.a1_b);
            gbar(cnt, gen);
            {
                GSeg segs[4] = { {A.a1_b, 2048, 0}, {A.a1_b + 512, 2048, 0},
                                 {A.a1_b + 1024, 2048, 0}, {A.a1_b + 1536, 2048, 0} };
                gemm_phase(bid, segs, A.comW2t + (long)ii * 2048 * 2048, 2048, 2048, 1, A.part);
            }
            gbar(cnt, gen);
            gate_phase(bid, sh, A.part, 8, 2048, 1536,
                       A.b_comb2 + ii * 2048, A.g_com + ii * 1536, A.beta_com + ii * 1536,
                       ii == NS - 1 ? inpf : A.cand_f + (ii + 1) * DD,
                       ii == NS - 1 ? TT * DD : NS * DD,
                       A.m_f + ii * DD, NS * DD,
                       A.cand_f + ii * DD, A.cand_b + ii * DD);
            gbar(cnt, gen);
        }

        {
            GSeg segs[4] = { {inpb, TT * DD, 0}, {A.task_b, DD, 0},
                             {A.m_b, NS * DD, DD}, {A.cand_b, NS * DD, DD} };
            gemm_phase(bid, segs, A.Wd1t, 2048, 512, 3, A.part);
        }
        gbar(cnt, gen);
        pbm_phase(bid, sh, A.part, A.b_bd1, A.w_Wd2, A.b_bd2, A.cand_f,
                  A.m_f, A.m_b, A.chl_f, A.pp, A.out,
                  (long)BB * TT * ACT + (long)t * (NS + 1), isf);
        gbar(cnt, gen);

        for (int j = 0; j < 2; ++j) {
            {
                GSeg segs[3] = { { j == 0 ? A.m_b : A.chl_b + DD, NS * DD, 0 },
                                 { inpb, TT * DD, 0 },
                                 { A.task_b, DD, 0 } };
                gemm_phase(bid, segs, A.decW1t + (long)j * 2048 * 1536, 1536, 2048, 1, A.part);
            }
            gbar(cnt, gen);
            reduce_phase(bid, A.part, 6, A.b_decb1 + j * 2048, A.a1_b);
            gbar(cnt, gen);
            {
                GSeg segs[4] = { {A.a1_b, 2048, 0}, {A.a1_b + 512, 2048, 0},
                                 {A.a1_b + 1024, 2048, 0}, {A.a1_b + 1536, 2048, 0} };
                gemm_phase(bid, segs, A.decW2t + (long)j * 1536 * 2048, 2048, 1536, 1, A.part);
            }
            gbar(cnt, gen);
            gate_phase(bid, sh, A.part, 8, 1536, 1024,
                       A.b_decb2 + j * 1536, A.g_dec + j * 1024, A.beta_dec + j * 1024,
                       j == 0 ? A.m_f : A.chl_f + DD, NS * DD,
                       nullptr, 0,
                       A.chl_f + (j + 1) * DD, A.chl_b + (j + 1) * DD);
            gbar(cnt, gen);
        }

        final_phase(bid, sh, A.chl_f, A.pp, A.task_f, inpf, A.w_Wa, A.b_ba,
                    A.out, (long)t * ACT, isf);
        gbar(cnt, gen);
    }
}

// ---------------- host ----------------
extern "C" void kernel_launch(void* const* d_in, const int* in_sizes, int n_in,
                              void* d_out, int out_size, void* d_ws, size_t ws_size,
                              hipStream_t stream) {
    const void* obs = d_in[0];
    const int* env = (const int*)d_in[1];
    const void* prevm = d_in[2];
    const void* emb = d_in[4];
    const void* Wobs = d_in[5];
    const void* bobs = d_in[6];
    const void* comW1 = d_in[7];
    const void* comb1 = d_in[8];
    const void* comW2 = d_in[9];
    const void* comb2 = d_in[10];
    const void* comg = d_in[11];
    const void* combeta = d_in[12];
    const void* decW1 = d_in[13];
    const void* decb1 = d_in[14];
    const void* decW2 = d_in[15];
    const void* decb2 = d_in[16];
    const void* decg = d_in[17];
    const void* decbeta = d_in[18];
    const void* Wd1 = d_in[19];
    const void* bd1 = d_in[20];
    const void* Wd2 = d_in[21];
    const void* bd2 = d_in[22];
    const void* Wa = d_in[23];
    const void* ba = d_in[24];

    char* p = (char*)d_ws;
    auto carve = [&](size_t bytes) -> char* {
        char* r = p;
        p += (bytes + 255) & ~(size_t)255;
        return r;
    };
    int* flag = (int*)carve(256);
    int* bar = (int*)carve(512);
    u16* comW1t = (u16*)carve(3ull * 2048 * 2048 * 2);
    u16* comW2t = (u16*)carve(3ull * 2048 * 2048 * 2);
    u16* decW1t = (u16*)carve(2ull * 2048 * 1536 * 2);
    u16* decW2t = (u16*)carve(2ull * 1536 * 2048 * 2);
    u16* Wd1t = (u16*)carve(512ull * 2048 * 2);
    u16* Wobst = (u16*)carve(512ull * 128 * 2);
    u16* obs_b = (u16*)carve((size_t)BB * TT * OBSD * 2);
    float* obs_inp_f = (float*)carve((size_t)BB * TT * DD * 4);
    u16* obs_inp_b = (u16*)carve((size_t)BB * TT * DD * 2);
    float* task_f = (float*)carve((size_t)BB * DD * 4);
    u16* task_b = (u16*)carve((size_t)BB * DD * 2);
    float* m_f = (float*)carve((size_t)BB * NS * DD * 4);
    u16* m_b = (u16*)carve((size_t)BB * NS * DD * 2);
    float* cand_f = (float*)carve((size_t)BB * NS * DD * 4);
    u16* cand_b = (u16*)carve((size_t)BB * NS * DD * 2);
    float* chl_f = (float*)carve((size_t)BB * NS * DD * 4);
    u16* chl_b = (u16*)carve((size_t)BB * NS * DD * 2);
    u16* a1_b = (u16*)carve((size_t)BB * 2048 * 2);
    float* part = (float*)carve(8ull * 64 * 2048 * 4);
    float* pp = (float*)carve((size_t)BB * 4 * 4);
    float* st_bobs = (float*)carve(512 * 4);
    float* st_comb1 = (float*)carve(3 * 2048 * 4);
    float* st_comb2 = (float*)carve(3 * 2048 * 4);
    float* st_comg = (float*)carve(3 * 1536 * 4);
    float* st_combeta = (float*)carve(3 * 1536 * 4);
    float* st_decb1 = (float*)carve(2 * 2048 * 4);
    float* st_decb2 = (float*)carve(2 * 1536 * 4);
    float* st_decg = (float*)carve(2 * 1024 * 4);
    float* st_decbeta = (float*)carve(2 * 1024 * 4);
    float* st_bd1 = (float*)carve(512 * 4);
    float* st_Wd2 = (float*)carve(512 * 4);
    float* st_bd2 = (float*)carve(256);
    float* st_Wa = (float*)carve(1536 * 15 * 4);
    float* st_ba = (float*)carve(15 * 4);

    dim3 blk(256);

    detect_k<<<dim3(1), dim3(64), 0, stream>>>(Wobs, flag, bar);

    {
        StageArgs sa{};
        const void* srcs[14] = {bobs, comb1, comb2, comg, combeta, decb1, decb2,
                                decg, decbeta, bd1, Wd2, bd2, Wa, ba};
        float* dsts[14] = {st_bobs, st_comb1, st_comb2, st_comg, st_combeta, st_decb1,
                           st_decb2, st_decg, st_decbeta, st_bd1, st_Wd2, st_bd2, st_Wa, st_ba};
        int ns[14] = {512, 6144, 6144, 4608, 4608, 4096, 3072, 2048, 2048, 512, 512, 1, 23040, 15};
        for (int i = 0; i < 14; ++i) { sa.src[i] = srcs[i]; sa.dst[i] = dsts[i]; sa.n[i] = ns[i]; }
        sa.flag = flag;
        stage_k<<<dim3(90, 14, 1), blk, 0, stream>>>(sa);
    }

    transpose_k<<<dim3(16, 4, 1), blk, 0, stream>>>(Wobs, Wobst, 128, 512, flag);
    transpose_k<<<dim3(64, 64, 3), blk, 0, stream>>>(comW1, comW1t, 2048, 2048, flag);
    transpose_k<<<dim3(64, 64, 3), blk, 0, stream>>>(comW2, comW2t, 2048, 2048, flag);
    transpose_k<<<dim3(64, 48, 2), blk, 0, stream>>>(decW1, decW1t, 1536, 2048, flag);
    transpose_k<<<dim3(48, 64, 2), blk, 0, stream>>>(decW2, decW2t, 2048, 1536, flag);
    transpose_k<<<dim3(16, 64, 1), blk, 0, stream>>>(Wd1, Wd1t, 2048, 512, flag);
    convb_k<<<dim3((BB * TT * OBSD + 255) / 256), blk, 0, stream>>>(obs, obs_b, BB * TT * OBSD, flag);
    init_k<<<dim3(BB), blk, 0, stream>>>(emb, env, prevm, task_f, task_b, m_b, m_f, flag);
    obsgemm_k<<<dim3(DD / 64, (BB * TT) / 64, 1), blk, 0, stream>>>(obs_b, Wobst, st_bobs,
                                                                    obs_inp_f, obs_inp_b);

    PArgs pa{};
    pa.comW1t = comW1t; pa.comW2t = comW2t; pa.decW1t = decW1t; pa.decW2t = decW2t; pa.Wd1t = Wd1t;
    pa.b_comb1 = st_comb1; pa.b_comb2 = st_comb2; pa.g_com = st_comg; pa.beta_com = st_combeta;
    pa.b_decb1 = st_decb1; pa.b_decb2 = st_decb2; pa.g_dec = st_decg; pa.beta_dec = st_decbeta;
    pa.b_bd1 = st_bd1; pa.w_Wd2 = st_Wd2; pa.b_bd2 = st_bd2; pa.w_Wa = st_Wa; pa.b_ba = st_ba;
    pa.obs_b_inp = obs_inp_b; pa.obs_f_inp = obs_inp_f;
    pa.task_b = task_b; pa.task_f = task_f;
    pa.m_b = m_b; pa.m_f = m_f; pa.cand_b = cand_b; pa.cand_f = cand_f;
    pa.chl_b = chl_b; pa.chl_f = chl_f; pa.a1_b = a1_b;
    pa.part = part; pa.pp = pp;
    pa.out = d_out; pa.flag = flag;
    pa.bar = bar;

    persist_k<<<dim3(NBLK), dim3(256), 0, stream>>>(pa);
}